// Round 5
// baseline (113.158 us; speedup 1.0000x reference)
//
#include <hip/hip_runtime.h>

// B=4, N=4096, D=128 fixed by the reference setup.
// d_ws layout: [0, 4MiB) h as bf16 bits (ushort), [4MiB, +64KiB) sq fp32.

typedef float  f32x4   __attribute__((ext_vector_type(4)));
typedef float  f32x16  __attribute__((ext_vector_type(16)));
typedef short  bf16x8  __attribute__((ext_vector_type(8)));

__device__ inline float bf2f(unsigned int u) {
    union { unsigned int i; float f; } c; c.i = u << 16; return c.f;
}
__device__ inline unsigned short f2bf(float f) {
    union { float f; unsigned int i; } c; c.f = f;
    unsigned int r = c.i + 0x7fffu + ((c.i >> 16) & 1u);   // RNE
    return (unsigned short)(r >> 16);
}

// ---------------- Kernel A: h = bf16(x @ W^T + b), plus sq[row] = ||h_row||^2 ----
#define KA_ROWS 32
__global__ __launch_bounds__(256) void proj_kernel(
    const float* __restrict__ x, const float* __restrict__ W,
    const float* __restrict__ bias, unsigned short* __restrict__ h,
    float* __restrict__ sq)
{
    __shared__ unsigned short Ws[128][136];
    __shared__ float          xs[KA_ROWS][132];
    const int t = threadIdx.x;
    const long r0 = (long)blockIdx.x * KA_ROWS;

    for (int q = t; q < 128 * 128 / 4; q += 256) {
        float4 w4 = ((const float4*)W)[q];
        int e = q >> 5, d = (q & 31) << 2;
        Ws[e][d + 0] = f2bf(w4.x); Ws[e][d + 1] = f2bf(w4.y);
        Ws[e][d + 2] = f2bf(w4.z); Ws[e][d + 3] = f2bf(w4.w);
    }
    const float4* xsrc = (const float4*)(x + r0 * 128);
    for (int q = t; q < KA_ROWS * 32; q += 256) {
        float4 v = xsrc[q];
        int r = q >> 5, d = (q & 31) << 2;
        xs[r][d] = v.x; xs[r][d + 1] = v.y; xs[r][d + 2] = v.z; xs[r][d + 3] = v.w;
    }
    __syncthreads();

    const int eb = t & 31, rb = t >> 5;
    const int e0 = eb * 4, rr0 = rb * 4;

    float acc_[4][4];
    #pragma unroll
    for (int ei = 0; ei < 4; ++ei) {
        float bv = bias[e0 + ei];
        #pragma unroll
        for (int ri = 0; ri < 4; ++ri) acc_[ri][ei] = bv;
    }

    for (int d = 0; d < 128; d += 4) {
        float wv[4][4];
        #pragma unroll
        for (int ei = 0; ei < 4; ++ei) {
            ushort4 u = *(const ushort4*)&Ws[e0 + ei][d];
            wv[ei][0] = bf2f(u.x); wv[ei][1] = bf2f(u.y);
            wv[ei][2] = bf2f(u.z); wv[ei][3] = bf2f(u.w);
        }
        #pragma unroll
        for (int ri = 0; ri < 4; ++ri) {
            float4 xv = *(const float4*)&xs[rr0 + ri][d];
            #pragma unroll
            for (int ei = 0; ei < 4; ++ei) {
                acc_[ri][ei] = fmaf(xv.x, wv[ei][0],
                               fmaf(xv.y, wv[ei][1],
                               fmaf(xv.z, wv[ei][2],
                               fmaf(xv.w, wv[ei][3], acc_[ri][ei]))));
            }
        }
    }

    float s[4] = {0.f, 0.f, 0.f, 0.f};
    #pragma unroll
    for (int ri = 0; ri < 4; ++ri) {
        ushort4 o;
        float v0 = bf2f(o.x = f2bf(acc_[ri][0]));
        float v1 = bf2f(o.y = f2bf(acc_[ri][1]));
        float v2 = bf2f(o.z = f2bf(acc_[ri][2]));
        float v3 = bf2f(o.w = f2bf(acc_[ri][3]));
        s[ri] = v0 * v0 + v1 * v1 + v2 * v2 + v3 * v3;
        *(ushort4*)&h[(r0 + rr0 + ri) * 128 + e0] = o;
    }
    #pragma unroll
    for (int ri = 0; ri < 4; ++ri) {
        #pragma unroll
        for (int m = 16; m > 0; m >>= 1) s[ri] += __shfl_xor(s[ri], m, 64);
    }
    if (eb == 0) {
        #pragma unroll
        for (int ri = 0; ri < 4; ++ri) sq[r0 + rr0 + ri] = s[ri];
    }
}

// ---------------- Kernel B: i-persistent gram, LDS-staged SEQUENTIAL writes ----
// Block owns 32 i-rows (contiguous 512 KB of out). Epilogue accumulates a
// 32x256 fp32 tile in LDS over 2 j-tiles, then flushes as per-wave 1 KB
// contiguous dwordx4 nt bursts, rows ascending — an orderly left-to-right
// sweep per block (write-locality experiment). j B-frags come straight from
// global (L2-hot, cross-block reuse) with 1-iteration register prefetch.
__global__ __launch_bounds__(256) void gram_kernel(
    const unsigned short* __restrict__ h, const float* __restrict__ sq,
    float* __restrict__ out)
{
    __shared__ float stage[32][256];                 // 32 KiB
    const int bid = blockIdx.x;
    const int xcd = bid & 7;
    const int bb  = xcd >> 1;                        // batch -> XCD pair
    const int itile = ((bid >> 3) << 1) | (xcd & 1); // 0..127
    const int i0l = itile * 32;
    const long jbase = (long)bb * 4096;
    const long ibase = jbase + i0l;
    const int t = threadIdx.x, w = t >> 6, lane = t & 63;
    const int l31 = lane & 31, lh = lane >> 5;
    const char* hb = (const char*)h;

    // A-fragments (32x32x16 A layout: row = lane&31, k-chunk = ks*2+lh)
    bf16x8 af[8];
    {
        const char* base = hb + ((ibase + l31) << 8);
        #pragma unroll
        for (int ks = 0; ks < 8; ++ks)
            af[ks] = *(const bf16x8*)(base + ((ks * 2 + lh) << 4));
    }
    float sqi_r[16];
    #pragma unroll
    for (int reg = 0; reg < 16; ++reg)
        sqi_r[reg] = sq[ibase + (reg & 3) + 8 * (reg >> 2) + 4 * lh];

    #define LOADB(dst, jt)                                                     \
        {                                                                      \
            const char* p_ = hb + ((jbase + (jt) * 128 + w * 32 + l31) << 8);  \
            _Pragma("unroll")                                                  \
            for (int ks = 0; ks < 8; ++ks)                                     \
                dst[ks] = *(const bf16x8*)(p_ + ((ks * 2 + lh) << 4));         \
        }

    #define COMPUTE(bg, jt)                                                    \
        {                                                                      \
            f32x16 acc = {};                                                   \
            _Pragma("unroll")                                                  \
            for (int ks = 0; ks < 8; ++ks)                                     \
                acc = __builtin_amdgcn_mfma_f32_32x32x16_bf16(                 \
                    af[ks], bg[ks], acc, 0, 0, 0);                             \
            const int jg = (jt) * 128 + w * 32 + l31;                          \
            const float sqj = sq[jbase + jg];                                  \
            const int cst = (((jt) & 1) << 7) + w * 32 + l31;                  \
            _Pragma("unroll")                                                  \
            for (int reg = 0; reg < 16; ++reg) {                               \
                int rl = (reg & 3) + 8 * (reg >> 2) + 4 * lh;                  \
                float d2 = fmaxf(sqi_r[reg] + sqj - 2.0f * acc[reg], 0.0f);    \
                float val = __expf(-sqrtf(d2));                                \
                if (i0l + rl == jg) val = 1.0f;                                \
                stage[rl][cst] = val;                                          \
            }                                                                  \
        }

    bf16x8 bgA[8], bgB[8];
    LOADB(bgA, 0);

    for (int jt = 0; jt < 32; jt += 2) {
        LOADB(bgB, jt + 1);
        COMPUTE(bgA, jt);
        if (jt + 2 < 32) LOADB(bgA, jt + 2);
        COMPUTE(bgB, jt + 1);
        __syncthreads();                    // stage tile complete (all waves)
        {
            const int jtp = jt >> 1;        // 256-col flush index
            #pragma unroll
            for (int k = 0; k < 8; ++k) {
                int r = w * 8 + k;
                f32x4 v = *(const f32x4*)&stage[r][lane << 2];
                long addr = ((jbase + i0l + r) << 12) + jtp * 256 + (lane << 2);
                __builtin_nontemporal_store(v, (f32x4*)&out[addr]);
            }
        }
        __syncthreads();                    // stage free for next pair
    }
    #undef LOADB
    #undef COMPUTE
}

extern "C" void kernel_launch(void* const* d_in, const int* in_sizes, int n_in,
                              void* d_out, int out_size, void* d_ws, size_t ws_size,
                              hipStream_t stream) {
    const float* x = (const float*)d_in[0];   // [4,4096,128]
    const float* W = (const float*)d_in[1];   // [128,128]
    const float* b = (const float*)d_in[2];   // [128]
    float* out = (float*)d_out;               // [4,4096,4096]

    unsigned short* h = (unsigned short*)d_ws;                       // 16384*128 bf16
    float* sq = (float*)((char*)d_ws + (size_t)16384 * 128 * 2);     // 16384 fp32

    proj_kernel<<<dim3(16384 / KA_ROWS), dim3(256), 0, stream>>>(x, W, b, h, sq);
    gram_kernel<<<dim3(512), dim3(256), 0, stream>>>(h, sq, out);
}

// Round 6
// 101.089 us; speedup vs baseline: 1.1194x; 1.1194x over previous
//
#include <hip/hip_runtime.h>

// B=4, N=4096, D=128 fixed by the reference setup.
// d_ws layout: [0, 4MiB) h as bf16 bits (ushort), [4MiB, +64KiB) sq fp32.

typedef float  f32x4   __attribute__((ext_vector_type(4)));
typedef float  f32x16  __attribute__((ext_vector_type(16)));
typedef short  bf16x8  __attribute__((ext_vector_type(8)));

__device__ inline float bf2f(unsigned int u) {
    union { unsigned int i; float f; } c; c.i = u << 16; return c.f;
}
__device__ inline unsigned short f2bf(float f) {
    union { float f; unsigned int i; } c; c.f = f;
    unsigned int r = c.i + 0x7fffu + ((c.i >> 16) & 1u);   // RNE
    return (unsigned short)(r >> 16);
}

// ---------------- Kernel A: h = bf16(x @ W^T + b), plus sq[row] = ||h_row||^2 ----
#define KA_ROWS 32
__global__ __launch_bounds__(256) void proj_kernel(
    const float* __restrict__ x, const float* __restrict__ W,
    const float* __restrict__ bias, unsigned short* __restrict__ h,
    float* __restrict__ sq)
{
    __shared__ unsigned short Ws[128][136];
    __shared__ float          xs[KA_ROWS][132];
    const int t = threadIdx.x;
    const long r0 = (long)blockIdx.x * KA_ROWS;

    for (int q = t; q < 128 * 128 / 4; q += 256) {
        float4 w4 = ((const float4*)W)[q];
        int e = q >> 5, d = (q & 31) << 2;
        Ws[e][d + 0] = f2bf(w4.x); Ws[e][d + 1] = f2bf(w4.y);
        Ws[e][d + 2] = f2bf(w4.z); Ws[e][d + 3] = f2bf(w4.w);
    }
    const float4* xsrc = (const float4*)(x + r0 * 128);
    for (int q = t; q < KA_ROWS * 32; q += 256) {
        float4 v = xsrc[q];
        int r = q >> 5, d = (q & 31) << 2;
        xs[r][d] = v.x; xs[r][d + 1] = v.y; xs[r][d + 2] = v.z; xs[r][d + 3] = v.w;
    }
    __syncthreads();

    const int eb = t & 31, rb = t >> 5;
    const int e0 = eb * 4, rr0 = rb * 4;

    float acc_[4][4];
    #pragma unroll
    for (int ei = 0; ei < 4; ++ei) {
        float bv = bias[e0 + ei];
        #pragma unroll
        for (int ri = 0; ri < 4; ++ri) acc_[ri][ei] = bv;
    }

    for (int d = 0; d < 128; d += 4) {
        float wv[4][4];
        #pragma unroll
        for (int ei = 0; ei < 4; ++ei) {
            ushort4 u = *(const ushort4*)&Ws[e0 + ei][d];
            wv[ei][0] = bf2f(u.x); wv[ei][1] = bf2f(u.y);
            wv[ei][2] = bf2f(u.z); wv[ei][3] = bf2f(u.w);
        }
        #pragma unroll
        for (int ri = 0; ri < 4; ++ri) {
            float4 xv = *(const float4*)&xs[rr0 + ri][d];
            #pragma unroll
            for (int ei = 0; ei < 4; ++ei) {
                acc_[ri][ei] = fmaf(xv.x, wv[ei][0],
                               fmaf(xv.y, wv[ei][1],
                               fmaf(xv.z, wv[ei][2],
                               fmaf(xv.w, wv[ei][3], acc_[ri][ei]))));
            }
        }
    }

    float s[4] = {0.f, 0.f, 0.f, 0.f};
    #pragma unroll
    for (int ri = 0; ri < 4; ++ri) {
        ushort4 o;
        float v0 = bf2f(o.x = f2bf(acc_[ri][0]));
        float v1 = bf2f(o.y = f2bf(acc_[ri][1]));
        float v2 = bf2f(o.z = f2bf(acc_[ri][2]));
        float v3 = bf2f(o.w = f2bf(acc_[ri][3]));
        s[ri] = v0 * v0 + v1 * v1 + v2 * v2 + v3 * v3;
        *(ushort4*)&h[(r0 + rr0 + ri) * 128 + e0] = o;
    }
    #pragma unroll
    for (int ri = 0; ri < 4; ++ri) {
        #pragma unroll
        for (int m = 16; m > 0; m >>= 1) s[ri] += __shfl_xor(s[ri], m, 64);
    }
    if (eb == 0) {
        #pragma unroll
        for (int ri = 0; ri < 4; ++ri) sq[r0 + rr0 + ri] = s[ri];
    }
}

// ---------------- Kernel B: barrier-free wave-independent gram ----------------
// One wave owns a 32(i) x 512(j) output strip. No LDS, no __syncthreads:
// A-frags + sq_i in registers; per j-step, B-frags read straight from the
// L2/L3-hot h panel (XCD affinity: 2 XCDs per batch). 16 waves/CU
// (__launch_bounds__(256,4)) so stores from some waves overlap loads/MFMA/
// transcendentals of others — components overlap instead of summing.
__global__ __launch_bounds__(256, 4) void gram_kernel(
    const unsigned short* __restrict__ h, const float* __restrict__ sq,
    float* __restrict__ out)
{
    const int bid = blockIdx.x;                      // 1024 blocks
    const int xcd = bid & 7;
    const int bb  = xcd >> 1;                        // batch -> XCD pair
    const int local = ((xcd & 1) << 7) | (bid >> 3); // 0..255 within batch
    const int i0l = (local >> 1) * 32;               // i-strip (128 per batch)
    const int w = threadIdx.x >> 6, lane = threadIdx.x & 63;
    const int l31 = lane & 31, lh = lane >> 5;
    const int j0 = (local & 1) * 2048 + w * 512;     // wave's j-range
    const long jbase = (long)bb * 4096;
    const long ibase = jbase + i0l;
    const char* hb = (const char*)h;

    // A-fragments (32x32x16 A layout: row = lane&31, k-chunk = ks*2+lh)
    bf16x8 af[8];
    {
        const char* base = hb + ((ibase + l31) << 8);
        #pragma unroll
        for (int ks = 0; ks < 8; ++ks)
            af[ks] = *(const bf16x8*)(base + ((ks * 2 + lh) << 4));
    }
    // sq_i per accumulator register (C/D row = (reg&3)+8*(reg>>2)+4*lh)
    float sqi_r[16];
    #pragma unroll
    for (int reg = 0; reg < 16; ++reg)
        sqi_r[reg] = sq[ibase + (reg & 3) + 8 * (reg >> 2) + 4 * lh];

    for (int js = 0; js < 16; ++js) {
        const int jc = j0 + js * 32 + l31;           // this lane's col (local)
        const char* bp = hb + ((jbase + jc) << 8);
        bf16x8 bg[8];
        #pragma unroll
        for (int ks = 0; ks < 8; ++ks)
            bg[ks] = *(const bf16x8*)(bp + ((ks * 2 + lh) << 4));
        f32x16 acc = {};
        #pragma unroll
        for (int ks = 0; ks < 8; ++ks)
            acc = __builtin_amdgcn_mfma_f32_32x32x16_bf16(af[ks], bg[ks], acc, 0, 0, 0);

        const float sqj = sq[jbase + jc];
        #pragma unroll
        for (int reg = 0; reg < 16; ++reg) {
            const int rl = (reg & 3) + 8 * (reg >> 2) + 4 * lh;
            float d2 = fmaxf(sqi_r[reg] + sqj - 2.0f * acc[reg], 0.0f);
            float val = __expf(-__builtin_amdgcn_sqrtf(d2));
            if (i0l + rl == jc) val = 1.0f;          // exact diagonal
            __builtin_nontemporal_store(val, &out[((ibase + rl) << 12) + jc]);
        }
    }
}

extern "C" void kernel_launch(void* const* d_in, const int* in_sizes, int n_in,
                              void* d_out, int out_size, void* d_ws, size_t ws_size,
                              hipStream_t stream) {
    const float* x = (const float*)d_in[0];   // [4,4096,128]
    const float* W = (const float*)d_in[1];   // [128,128]
    const float* b = (const float*)d_in[2];   // [128]
    float* out = (float*)d_out;               // [4,4096,4096]

    unsigned short* h = (unsigned short*)d_ws;                       // 16384*128 bf16
    float* sq = (float*)((char*)d_ws + (size_t)16384 * 128 * 2);     // 16384 fp32

    proj_kernel<<<dim3(16384 / KA_ROWS), dim3(256), 0, stream>>>(x, W, b, h, sq);
    gram_kernel<<<dim3(1024), dim3(256), 0, stream>>>(h, sq, out);
}